// Round 1
// baseline (99074.420 us; speedup 1.0000x reference)
//
#include <hip/hip_runtime.h>

// =====================================================================
// AutoregressiveSubsetSampler — persistent cooperative kernel, MI355X.
// Round 5: line-padded fp64 accumulators (each element on its own 128B
// line -> same-line RMW serialization 1024 -> 64 per round), fused
// single-pass LN statistics (sum + sumsq in one block reduction),
// arrive/wait-split grid barrier with m(t+1)/u(t+1) prefetch in the
// poll gaps, parallel 4-lane count fetch in stage C.
//
// Per step t:
//  stage A: h1 slice local (rows 8b..8b+8) -> px/h partials atomicAdd
//           (padded) -> arrive B1 -> [m(t+1) prefetch] -> wait B1
//  stage B: read px,h; fused ln1 -> x; f1 slice LOCAL (LDS);
//           logits slice -> sampling -> counts; pg partial atomicAdd;
//           WG1 zeroes next-parity accumulators -> arrive B2 ->
//           [u(t+1) prefetch] -> wait B2
//  stage C: read pg + counts(4 lanes); fused ln2 -> g; pick attempt;
//           write row.
// All fp64 on the logit-critical chain (binary output: ~1e-13 margin).
// =====================================================================

typedef unsigned int u32;

#define NWG   64
#define NT    256
#define NSTEP 8192

// ---- relaxed agent-scope (LLC-direct, cache-bypassing) ops ----
__device__ __forceinline__ double gld(const double* p) {
  return __hip_atomic_load(p, __ATOMIC_RELAXED, __HIP_MEMORY_SCOPE_AGENT);
}
__device__ __forceinline__ void gst(double* p, double v) {
  __hip_atomic_store(p, v, __ATOMIC_RELAXED, __HIP_MEMORY_SCOPE_AGENT);
}
__device__ __forceinline__ u32 gldu(const u32* p) {
  return __hip_atomic_load(p, __ATOMIC_RELAXED, __HIP_MEMORY_SCOPE_AGENT);
}
__device__ __forceinline__ void gstu(u32* p, u32 v) {
  __hip_atomic_store(p, v, __ATOMIC_RELAXED, __HIP_MEMORY_SCOPE_AGENT);
}
__device__ __forceinline__ void gstf(float* p, float v) {
  __hip_atomic_store(p, v, __ATOMIC_RELAXED, __HIP_MEMORY_SCOPE_AGENT);
}
// fp64 atomic add -> global_atomic_add_f64 (HW instr on gfx90a+/gfx950)
__device__ __forceinline__ void gadd(double* p, double v) {
  unsafeAtomicAdd(p, v);
}

// ---- flag-array grid barrier, split into arrive / wait so independent
// prefetch loads can issue inside the poll window.
// __syncthreads in arrive drains each wave's vmcnt before lane 0 raises
// its flag -> all of the WG's global stores/atomics are LLC-acked first.
__device__ __forceinline__ void gbar_arrive(u32* flags, u32 e) {
  __syncthreads();
  if (threadIdx.x == 0) gstu(&flags[blockIdx.x], e);
}
__device__ __forceinline__ void gbar_wait(u32* flags, u32 e) {
  if (threadIdx.x < 64) {
    while (gldu(&flags[threadIdx.x]) < e) { }
  }
  asm volatile("" ::: "memory");
  __syncthreads();
}

// fused block-wide (sum, sum-of-squares) of one double per thread.
// Deterministic order per WG; redundant WGs execute identical sequences
// -> bitwise-identical results across all 64 WGs.
__device__ __forceinline__ void block_sum2(double v, double* sred,
                                           double& s1, double& s2) {
  double w = v * v;
  #pragma unroll
  for (int off = 32; off; off >>= 1) {
    v += __shfl_down(v, off);
    w += __shfl_down(w, off);
  }
  __syncthreads();
  if ((threadIdx.x & 63) == 0) {
    int q = threadIdx.x >> 6;
    sred[2 * q] = v; sred[2 * q + 1] = w;
  }
  __syncthreads();
  s1 = sred[0] + sred[2] + sred[4] + sred[6];
  s2 = sred[1] + sred[3] + sred[5] + sred[7];
}

// ---------------------------------------------------------------------
// prep kernels (every launch; ~100us, fp64)
// ---------------------------------------------------------------------
__global__ void prep_zero(u32* hdr) {
  int i = blockIdx.x * 256 + threadIdx.x;
  // hdr/flags/counts (4KB) + 3 line-padded [2][256] fp64 accumulators
  // (3 * 64KB) = 200704 bytes = 50176 u32
  if (i < 50176) hdr[i] = 0u;
}

// Wg2 = Wg @ W2   [256x512];  c1 = Wg@b2 + bg
__global__ __launch_bounds__(256) void prep_mm1(const float* __restrict__ Wg,
    const float* __restrict__ W2, const float* __restrict__ b2,
    const float* __restrict__ bg, double* __restrict__ Wg2d, double* __restrict__ c1d) {
  int i = threadIdx.x, j = blockIdx.x;
  double acc = 0.0;
  for (int k = 0; k < 256; k++) acc += (double)Wg[i * 256 + k] * (double)W2[k * 512 + j];
  Wg2d[(size_t)i * 512 + j] = acc;
  if (j == 0) {
    double c = 0.0;
    for (int k = 0; k < 256; k++) c += (double)Wg[i * 256 + k] * (double)b2[k];
    c1d[i] = c + (double)bg[i];
  }
}

// Wov = Wo @ Wv  [256x256];  c2 = Wo@bv + bo
__global__ __launch_bounds__(256) void prep_mm2(const float* __restrict__ Wo,
    const float* __restrict__ Wv, const float* __restrict__ bv,
    const float* __restrict__ bo, double* __restrict__ Wovd, double* __restrict__ c2d) {
  int i = threadIdx.x, j = blockIdx.x;
  double acc = 0.0;
  for (int k = 0; k < 256; k++) acc += (double)Wo[i * 256 + k] * (double)Wv[k * 256 + j];
  Wovd[i * 256 + j] = acc;
  if (j == 0) {
    double c = 0.0;
    for (int k = 0; k < 256; k++) c += (double)Wo[i * 256 + k] * (double)bv[k];
    c2d[i] = c + (double)bo[i];
  }
}

// Awg = (I + Wov) @ Wg2  [256x512];  c3 = (I+Wov)@c1 + c2
__global__ __launch_bounds__(256) void prep_mm3(const double* __restrict__ Wg2d,
    const double* __restrict__ Wovd, const double* __restrict__ c1d,
    const double* __restrict__ c2d, double* __restrict__ Awgd, double* __restrict__ c3d) {
  int i = threadIdx.x, j = blockIdx.x;
  double acc = Wg2d[(size_t)i * 512 + j];
  for (int k = 0; k < 256; k++) acc += Wovd[i * 256 + k] * Wg2d[(size_t)k * 512 + j];
  Awgd[(size_t)i * 512 + j] = acc;
  if (j == 0) {
    double c = c1d[i] + c2d[i];
    for (int k = 0; k < 256; k++) c += Wovd[i * 256 + k] * c1d[k];
    c3d[i] = c;
  }
}

// ---------------------------------------------------------------------
// main persistent kernel: 64 WGs x 256 threads, 8192 steps, 2 barriers/step
// accumulator layout: element i of parity p lives at ((p*256 + i) << 4)
// doubles -> one 128B line per element -> 64 same-line RMWs per round
// (one per WG) instead of 1024.
// ---------------------------------------------------------------------
__global__ __launch_bounds__(256) void sampler_main(
    const float* __restrict__ gnn, const float* __restrict__ u,
    const float* __restrict__ W1, const float* __restrict__ b1,
    const float* __restrict__ W2, const float* __restrict__ b2,
    const float* __restrict__ Wr, const float* __restrict__ br,
    const float* __restrict__ Wf1, const float* __restrict__ bf1,
    const float* __restrict__ Wf2, const float* __restrict__ bf2,
    const float* __restrict__ ln1g, const float* __restrict__ ln1b,
    const float* __restrict__ ln2g, const float* __restrict__ ln2b,
    const double* __restrict__ Awgd, const double* __restrict__ c3d,
    double* __restrict__ pxbuf, double* __restrict__ hbuf,
    double* __restrict__ pgbuf, u32* __restrict__ hdr,
    float* __restrict__ out) {

  __shared__ double smg[512];        // [ m_t ; g ]
  __shared__ double sh1[8];          // local h1 slice (k-cols 8b..8b+8)
  __shared__ double sx [256];        // x = ln1(px)
  __shared__ double shh[256];        // h broadcast
  __shared__ double sf1[32];         // local f1 slice
  __shared__ double sprob[32];
  __shared__ double sred[8];
  __shared__ u32 ssamp[4];
  __shared__ u32 scnt[4];
  __shared__ int sidx;

  const int b = blockIdx.x, tid = threadIdx.x;
  u32* flags  = hdr;                 // 64 contiguous u32
  u32* counts = hdr + 96;            // [2][4] u32, stride 32

  // ---- per-thread weight slices -> registers ----
  const int r1 = tid >> 5, l1 = tid & 31;     // stage A: W1 row 8b+r1
  float w1reg[16];
  #pragma unroll
  for (int k = 0; k < 16; k++) w1reg[k] = W1[(size_t)(8 * b + r1) * 512 + l1 + 32 * k];

  // K-col slices: this thread owns OUTPUT index tid, K-cols 8b..8b+8
  double areg[8]; float w2reg[8];
  #pragma unroll
  for (int k = 0; k < 8; k++) {
    areg[k]  = Awgd[(size_t)tid * 512 + 8 * b + k];
    w2reg[k] = W2  [(size_t)tid * 512 + 8 * b + k];
  }
  const int r3 = tid >> 3, l3 = tid & 7;      // stage B: rows 32b+r3
  float f1reg[32], wrreg[32];
  #pragma unroll
  for (int k = 0; k < 32; k++) {
    f1reg[k] = Wf1[(size_t)(32 * b + r3) * 256 + l3 + 8 * k];
    wrreg[k] = Wr [(size_t)(32 * b + r3) * 256 + l3 + 8 * k];
  }
  // Wf2 K-col slice: output tid, K-cols 32b..32b+32
  float f2reg[32];
  #pragma unroll
  for (int k = 0; k < 32; k++) f2reg[k] = Wf2[(size_t)tid * 2048 + 32 * b + k];

  // per-thread constants
  const double ln1gv = (double)ln1g[tid], ln1bv = (double)ln1b[tid];
  const double ln2gv = (double)ln2g[tid], ln2bv = (double)ln2b[tid];
  const double b1v  = (double)b1 [8 * b + r1];
  const double b2v  = (double)b2 [tid];
  const double c3v  =          c3d[tid];
  const double bf1v = (double)bf1[32 * b + r3];
  const double brv  = (double)br [32 * b + r3];
  const double bf2v = (double)bf2[tid];

  // initial state: m(0) = gnn row 0, g0 = 0
  smg[tid]       = (double)gnn[tid];
  smg[256 + tid] = 0.0;
  __syncthreads();

  // u(0) prefetch
  float ureg = 0.0f;
  if (tid < 128)
    ureg = u[(size_t)(tid >> 5) * 2048 + 32 * b + (tid & 31)];

  for (int t = 0; t < NSTEP; ++t) {
    const int p = t & 1;
    double* pxp = pxbuf + (p << 12);   // p*256 elements * 16 doubles
    double* hp_ = hbuf  + (p << 12);
    double* pgp = pgbuf + (p << 12);
    u32*   cntp = counts + p * 4 * 32;

    // ================= stage A =================
    {
      double acc = 0.0;                         // h1 slice, rows 8b..8b+7
      #pragma unroll
      for (int k = 0; k < 16; k++) acc += (double)w1reg[k] * smg[l1 + 32 * k];
      #pragma unroll
      for (int off = 16; off; off >>= 1) acc += __shfl_down(acc, off, 32);
      if (l1 == 0) { double v = acc + b1v; sh1[r1] = (v > 0.0) ? v : 0.0; }
    }
    __syncthreads();
    {
      double pxv = 0.0, hv = 0.0;               // K-partials for px, h
      #pragma unroll
      for (int k = 0; k < 8; k++) {
        double h1k = sh1[k];
        pxv += areg[k] * h1k; hv += (double)w2reg[k] * h1k;
      }
      if (b == 0) { pxv += c3v; hv += b2v; }
      gadd(&pxp[tid << 4], pxv); gadd(&hp_[tid << 4], hv);
    }
    gbar_arrive(flags, 2 * t + 1);              // B1: px, h complete
    float mnf = gnn[(size_t)((t + 1) & 4095) * 256 + tid];  // m(t+1) prefetch
    gbar_wait(flags, 2 * t + 1);

    // ================= stage B =================
    double pxv = gld(&pxp[tid << 4]);
    double hv  = gld(&hp_[tid << 4]);
    shh[tid] = hv;
    double xv;
    {
      double s1, s2; block_sum2(pxv, sred, s1, s2);
      double mu  = s1 * (1.0 / 256.0);
      double var = s2 * (1.0 / 256.0) - mu * mu;
      xv = (pxv - mu) * (1.0 / sqrt(var + 1e-5)) * ln1gv + ln1bv;
    }
    sx[tid]  = xv;
    smg[tid] = (double)mnf;                      // m(t+1); h1 dot done pre-B1
    __syncthreads();
    {
      double accF = 0.0, accL = 0.0;             // f1 rows + logit rows 32b+r3
      #pragma unroll
      for (int k = 0; k < 32; k++) {
        int j = l3 + 8 * k;
        accF += (double)f1reg[k] * sx[j];
        accL += (double)wrreg[k] * shh[j];
      }
      #pragma unroll
      for (int off = 4; off; off >>= 1) { accF += __shfl_down(accF, off, 8); accL += __shfl_down(accL, off, 8); }
      if (l3 == 0) {
        double fv = accF + bf1v;
        sf1[r3]   = (fv > 0.0) ? fv : 0.0;       // local f1 slice -> LDS only
        sprob[r3] = 1.0 / (1.0 + exp(-(accL + brv)));
      }
    }
    __syncthreads();
    if (tid < 128) {                             // sampling + exact counts
      int a = tid >> 5;
      bool pred = ((double)ureg < sprob[tid & 31]);
      unsigned long long bal = __ballot(pred);
      int l64 = tid & 63;
      if (l64 == 0) {
        u32 mm = (u32)(bal & 0xffffffffull);
        ssamp[a] = mm; atomicAdd(&cntp[a * 32], (u32)__popc(mm));
      } else if (l64 == 32) {
        u32 mm = (u32)(bal >> 32);
        ssamp[a] = mm; atomicAdd(&cntp[a * 32], (u32)__popc(mm));
      }
    }
    {
      double pgv = 0.0;                          // pg K-partial
      #pragma unroll
      for (int k = 0; k < 32; k++) pgv += (double)f2reg[k] * sf1[k];
      if (b == 0) pgv += xv + bf2v;
      gadd(&pgp[tid << 4], pgv);
    }
    if (b == 1) {                                // zero next-parity accums
      gst(&pxbuf[(((1 - p) << 8) + tid) << 4], 0.0);
      gst(&hbuf [(((1 - p) << 8) + tid) << 4], 0.0);
      gst(&pgbuf[(((1 - p) << 8) + tid) << 4], 0.0);
      if (tid < 4) gstu(&counts[(1 - p) * 4 * 32 + tid * 32], 0u);
    }
    gbar_arrive(flags, 2 * t + 2);               // B2: pg, counts complete
    float unext = 0.0f;                          // u(t+1) prefetch (HBM)
    if (tid < 128 && t < NSTEP - 1)
      unext = u[((size_t)(t + 1) * 4 + (tid >> 5)) * 2048 + 32 * b + (tid & 31)];
    gbar_wait(flags, 2 * t + 2);

    // ================= stage C =================
    double pgv = gld(&pgp[tid << 4]);
    if (tid < 4) scnt[tid] = gldu(&cntp[tid * 32]);   // parallel count fetch
    {
      double s1, s2; block_sum2(pgv, sred, s1, s2);
      double mu  = s1 * (1.0 / 256.0);
      double var = s2 * (1.0 / 256.0) - mu * mu;
      smg[256 + tid] = (pgv - mu) * (1.0 / sqrt(var + 1e-5)) * ln2gv + ln2bv;
    }
    if (tid == 0) {
      int idx = 0;
      #pragma unroll
      for (int a = 3; a >= 0; a--) {
        u32 c = scnt[a];
        if (c == 0u || (c >= 2u && c <= 6u)) idx = a;
      }
      sidx = idx;
    }
    __syncthreads();
    if (tid < 32) {
      u32 mm = ssamp[sidx];
      gstf(&out[(size_t)t * 2048 + 32 * b + tid], ((mm >> tid) & 1u) ? 1.0f : 0.0f);
    }
    ureg = unext;
  }
}

// ---------------------------------------------------------------------
extern "C" void kernel_launch(void* const* d_in, const int* in_sizes, int n_in,
                              void* d_out, int out_size, void* d_ws, size_t ws_size,
                              hipStream_t stream) {
  const float* gnn = (const float*)d_in[0];
  const float* u   = (const float*)d_in[2];
  const float* W1  = (const float*)d_in[3];
  const float* b1  = (const float*)d_in[4];
  const float* W2  = (const float*)d_in[5];
  const float* b2  = (const float*)d_in[6];
  const float* Wr  = (const float*)d_in[7];
  const float* br  = (const float*)d_in[8];
  const float* Wg  = (const float*)d_in[9];
  const float* bg  = (const float*)d_in[10];
  const float* Wv  = (const float*)d_in[11];
  const float* bv  = (const float*)d_in[12];
  const float* Wo  = (const float*)d_in[13];
  const float* bo  = (const float*)d_in[14];
  const float* Wf1 = (const float*)d_in[15];
  const float* bf1 = (const float*)d_in[16];
  const float* Wf2 = (const float*)d_in[17];
  const float* bf2 = (const float*)d_in[18];
  const float* ln1g = (const float*)d_in[19];
  const float* ln1b = (const float*)d_in[20];
  const float* ln2g = (const float*)d_in[21];
  const float* ln2b = (const float*)d_in[22];
  float* out = (float*)d_out;

  // workspace layout:
  //   [0, 4KB)        flags (64 u32) + counts ([2][4] u32, stride 32)
  //   [4KB, 68KB)     pxbuf  [2][256] fp64, 128B line-padded (<<4)
  //   [68KB, 132KB)   hbuf   same layout
  //   [132KB, 196KB)  pgbuf  same layout
  //   [200KB, ...)    prep fp64 weights
  u32* hdr = (u32*)d_ws;
  double* pxbuf = (double*)((char*)d_ws + 4096);    // 2*256*16 doubles = 64KB
  double* hbuf  = pxbuf + 8192;
  double* pgbuf = hbuf  + 8192;
  double* base  = (double*)((char*)d_ws + 204800);
  double* c1d   = base;            // 256
  double* c2d   = c1d + 256;       // 256
  double* c3d   = c2d + 256;       // 256
  double* Wg2d  = c3d + 256;       // 131072
  double* Wovd  = Wg2d + 131072;   // 65536
  double* Awgd  = Wovd + 65536;    // 131072

  hipLaunchKernelGGL(prep_zero, dim3(196), dim3(256), 0, stream, hdr);
  hipLaunchKernelGGL(prep_mm1, dim3(512), dim3(256), 0, stream, Wg, W2, b2, bg, Wg2d, c1d);
  hipLaunchKernelGGL(prep_mm2, dim3(256), dim3(256), 0, stream, Wo, Wv, bv, bo, Wovd, c2d);
  hipLaunchKernelGGL(prep_mm3, dim3(512), dim3(256), 0, stream, Wg2d, Wovd, c1d, c2d, Awgd, c3d);
  hipLaunchKernelGGL(sampler_main, dim3(NWG), dim3(NT), 0, stream,
                     gnn, u, W1, b1, W2, b2, Wr, br, Wf1, bf1, Wf2, bf2,
                     ln1g, ln1b, ln2g, ln2b, Awgd, c3d,
                     pxbuf, hbuf, pgbuf, hdr, out);
}